// Round 9
// baseline (463.104 us; speedup 1.0000x reference)
//
#include <hip/hip_runtime.h>

#define DD 32
#define EPSF 1e-16f
#define SCAN_T 1024
#define BSH 6                    // 64 nodes per bucket
#define BMAX 1024                // max buckets (N <= 65536)
#define K3_TPB 256
#define K3_EPT 16
#define K3_EPB (K3_TPB * K3_EPT) // 4096 edges per binning block
// NOTE: eid packed into 21 bits -> requires E < 2^21 (= 2,097,152). E = 1.6M ok.

// ---- K1: block-local histogram of coarse buckets ----
__launch_bounds__(K3_TPB)
__global__ void hist_kernel(const int* __restrict__ index,
                            int* __restrict__ bcnt, int E, int B) {
    __shared__ int lcnt[BMAX];
    int t = threadIdx.x;
    int base = blockIdx.x * K3_EPB;
    int nE = min(K3_EPB, E - base);

    for (int b = t; b < B; b += K3_TPB) lcnt[b] = 0;
    __syncthreads();
    for (int off = t; off < nE; off += K3_TPB)
        atomicAdd(&lcnt[index[base + off] >> BSH], 1);
    __syncthreads();
    for (int b = t; b < B; b += K3_TPB)
        if (lcnt[b]) atomicAdd(&bcnt[b], lcnt[b]);
}

// ---- K2: exclusive scan of bcnt[B] -> boff[B+1], bcursor ----
__global__ void scan_kernel(const int* __restrict__ bcnt, int* __restrict__ boff,
                            int* __restrict__ bcursor, int B) {
    __shared__ int part[SCAN_T];
    int t = threadIdx.x;
    int chunk = (B + SCAN_T - 1) / SCAN_T;
    int lo = t * chunk;
    int hi = min(lo + chunk, B);
    int s = 0;
    for (int i = lo; i < hi; ++i) s += bcnt[i];
    part[t] = s;
    __syncthreads();
    for (int d = 1; d < SCAN_T; d <<= 1) {
        int v = (t >= d) ? part[t - d] : 0;
        __syncthreads();
        part[t] += v;
        __syncthreads();
    }
    int run = (t == 0) ? 0 : part[t - 1];
    for (int i = lo; i < hi; ++i) {
        boff[i] = run;
        bcursor[i] = run;
        run += bcnt[i];
    }
    if (t == SCAN_T - 1) boff[B] = run;  // == E
}

// ---- K3: two-pass bin + fused score; writes (eid|nloc, ex) pairs ----
__launch_bounds__(K3_TPB)
__global__ void binscore_kernel(const float* __restrict__ ax,
                                const int* __restrict__ index,
                                const float* __restrict__ Wsf,
                                const float* __restrict__ bsf,
                                int* __restrict__ bcursor,
                                uint2* __restrict__ pairs, int E, int B) {
    __shared__ int lcnt[BMAX];
    __shared__ int lbase[BMAX];
    int t = threadIdx.x;
    int base = blockIdx.x * K3_EPB;
    int nE = min(K3_EPB, E - base);

    for (int b = t; b < B; b += K3_TPB) lcnt[b] = 0;
    __syncthreads();

    // pass 1: count (cache idx in registers)
    int idxv[K3_EPT];
#pragma unroll
    for (int i = 0; i < K3_EPT; ++i) {
        int off = i * K3_TPB + t;
        idxv[i] = -1;
        if (off < nE) {
            idxv[i] = index[base + off];
            atomicAdd(&lcnt[idxv[i] >> BSH], 1);
        }
    }
    __syncthreads();

    // alloc global chunk per bucket; reset count for pass 2.
    // each bucket b is touched by exactly one thread (b mod 256 == t).
    for (int b = t; b < B; b += K3_TPB) {
        int c = lcnt[b];
        lbase[b] = (c > 0) ? atomicAdd(&bcursor[b], c) : 0;
        lcnt[b] = 0;
    }
    __syncthreads();

    // pass 2: compute score+exp, place pair
    float bsv = bsf[0];
#pragma unroll
    for (int i = 0; i < K3_EPT; ++i) {
        int off = i * K3_TPB + t;
        if (off >= nE) continue;
        int e = base + off;
        const float4* r = reinterpret_cast<const float4*>(ax + (size_t)e * DD);
        float s = bsv;
#pragma unroll
        for (int q = 0; q < 8; ++q) {
            float4 f = r[q];
            s = fmaf(f.x, Wsf[4 * q],     s);
            s = fmaf(f.y, Wsf[4 * q + 1], s);
            s = fmaf(f.z, Wsf[4 * q + 2], s);
            s = fmaf(f.w, Wsf[4 * q + 3], s);
        }
        float exv = __expf(s);
        int idx = idxv[i];
        int b = idx >> BSH;
        int pos = atomicAdd(&lcnt[b], 1);
        pairs[lbase[b] + pos] =
            make_uint2((unsigned)e | ((unsigned)(idx & ((1 << BSH) - 1)) << 21),
                       __float_as_uint(exv));
    }
}

// ---- K4: one block per bucket — one THREAD per edge, LDS atomic accumulate ----
// (deliberately simple: no shuffles, no parity unroll — isolating round 6-8 bug)
__launch_bounds__(256)
__global__ void aggregate_kernel(const float* __restrict__ x,
                                 const uint2* __restrict__ pairs,
                                 const int* __restrict__ boff,
                                 const float* __restrict__ Wf,   // [DD][DD]
                                 const float* __restrict__ bfv,  // [DD]
                                 float* __restrict__ out, int N) {
    __shared__ float acc[64][DD + 1];   // [node][0..31]=sum ex*x, [32]=sum ex
    int bk = blockIdx.x;
    int nbase = bk << BSH;
    int t = threadIdx.x;

    for (int i = t; i < 64 * (DD + 1); i += 256) ((float*)acc)[i] = 0.0f;
    __syncthreads();

    int beg = boff[bk], end = boff[bk + 1];
    for (int p = beg + t; p < end; p += 256) {
        uint2 pr = pairs[p];
        unsigned eid = pr.x & 0x1FFFFFu;
        int nloc = (int)((pr.x >> 21) & 63u);
        float w = __uint_as_float(pr.y);
        const float4* xr = reinterpret_cast<const float4*>(x + (size_t)eid * DD);
        float* arow = acc[nloc];
#pragma unroll
        for (int q = 0; q < 8; ++q) {
            float4 f = xr[q];
            atomicAdd(&arow[4 * q],     w * f.x);
            atomicAdd(&arow[4 * q + 1], w * f.y);
            atomicAdd(&arow[4 * q + 2], w * f.z);
            atomicAdd(&arow[4 * q + 3], w * f.w);
        }
        atomicAdd(&arow[DD], w);
    }
    __syncthreads();

    // epilogue: thread t -> node n = t>>2, output cols j0..j0+7
    int n = t >> 2;
    int node = nbase + n;
    if (node < N) {
        float d = acc[n][DD];
        float inv = 1.0f / (d + EPSF);
        float sw = d * inv;
        int j0 = (t & 3) * 8;
        float o[8];
#pragma unroll
        for (int jj = 0; jj < 8; ++jj) o[jj] = sw * bfv[j0 + jj];
#pragma unroll
        for (int kk = 0; kk < DD; ++kk) {
            float y = acc[n][kk] * inv;
            const float* Wrow = Wf + kk * DD + j0;
#pragma unroll
            for (int jj = 0; jj < 8; ++jj) o[jj] = fmaf(y, Wrow[jj], o[jj]);
        }
        float4* o4 = reinterpret_cast<float4*>(out + (size_t)node * DD + j0);
        o4[0] = make_float4(o[0], o[1], o[2], o[3]);
        o4[1] = make_float4(o[4], o[5], o[6], o[7]);
    }
}

extern "C" void kernel_launch(void* const* d_in, const int* in_sizes, int n_in,
                              void* d_out, int out_size, void* d_ws, size_t ws_size,
                              hipStream_t stream) {
    const float* x       = (const float*)d_in[0];
    const float* ax      = (const float*)d_in[1];
    const int*   index   = (const int*)d_in[2];
    // d_in[3] = size scalar; N derived from out_size
    const float* W_emb   = (const float*)d_in[4];
    const float* b_emb   = (const float*)d_in[5];
    const float* W_score = (const float*)d_in[6];
    const float* b_score = (const float*)d_in[7];

    int E = in_sizes[0] / DD;
    int N = out_size / DD;
    int B = (N + (1 << BSH) - 1) >> BSH;   // 782 for N=50000 (<= BMAX)

    // workspace layout: pairs[E] (12.8 MB) + ~10 KB of counters.
    uint2* pairs   = (uint2*)d_ws;                    // [E]
    int*   bcnt    = (int*)(pairs + (size_t)E);       // [B]
    int*   boff    = bcnt + B;                        // [B+1]
    int*   bcursor = boff + B + 1;                    // [B]

    hipMemsetAsync(bcnt, 0, sizeof(int) * (size_t)B, stream);

    int blocksK = (E + K3_EPB - 1) / K3_EPB;
    hist_kernel<<<blocksK, K3_TPB, 0, stream>>>(index, bcnt, E, B);
    scan_kernel<<<1, SCAN_T, 0, stream>>>(bcnt, boff, bcursor, B);
    binscore_kernel<<<blocksK, K3_TPB, 0, stream>>>(ax, index, W_score, b_score,
                                                    bcursor, pairs, E, B);
    aggregate_kernel<<<B, 256, 0, stream>>>(x, pairs, boff, W_emb, b_emb,
                                            (float*)d_out, N);
}

// Round 10
// 208.988 us; speedup vs baseline: 2.2159x; 2.2159x over previous
//
#include <hip/hip_runtime.h>

#define DD 32
#define EPSF 1e-16f
#define SCAN_T 1024
#define BSH 5                    // 32 nodes per bucket
#define BNODES (1 << BSH)
#define BMAX 2048                // max buckets (N <= 65536)
#define K3_TPB 256
#define K3_EPT 16
#define K3_EPB (K3_TPB * K3_EPT) // 4096 edges per binning block
#define CHUNK 1536               // pairs per aggregate LDS chunk
// NOTE: eid packed into 21 bits -> requires E < 2^21. E = 1.6M ok.

// ---- K1: block-local histogram of coarse buckets ----
__launch_bounds__(K3_TPB)
__global__ void hist_kernel(const int* __restrict__ index,
                            int* __restrict__ bcnt, int E, int B) {
    __shared__ int lcnt[BMAX];
    int t = threadIdx.x;
    int base = blockIdx.x * K3_EPB;
    int nE = min(K3_EPB, E - base);

    for (int b = t; b < B; b += K3_TPB) lcnt[b] = 0;
    __syncthreads();
    for (int off = t; off < nE; off += K3_TPB)
        atomicAdd(&lcnt[index[base + off] >> BSH], 1);
    __syncthreads();
    for (int b = t; b < B; b += K3_TPB)
        if (lcnt[b]) atomicAdd(&bcnt[b], lcnt[b]);
}

// ---- K2: exclusive scan of bcnt[B] -> boff[B+1], bcursor ----
__global__ void scan_kernel(const int* __restrict__ bcnt, int* __restrict__ boff,
                            int* __restrict__ bcursor, int B) {
    __shared__ int part[SCAN_T];
    int t = threadIdx.x;
    int chunk = (B + SCAN_T - 1) / SCAN_T;
    int lo = t * chunk;
    int hi = min(lo + chunk, B);
    int s = 0;
    for (int i = lo; i < hi; ++i) s += bcnt[i];
    part[t] = s;
    __syncthreads();
    for (int d = 1; d < SCAN_T; d <<= 1) {
        int v = (t >= d) ? part[t - d] : 0;
        __syncthreads();
        part[t] += v;
        __syncthreads();
    }
    int run = (t == 0) ? 0 : part[t - 1];
    for (int i = lo; i < hi; ++i) {
        boff[i] = run;
        bcursor[i] = run;
        run += bcnt[i];
    }
    if (t == SCAN_T - 1) boff[B] = run;  // == E
}

// ---- K3: two-pass bin + fused score; writes (eid|nloc, ex) pairs ----
__launch_bounds__(K3_TPB)
__global__ void binscore_kernel(const float* __restrict__ ax,
                                const int* __restrict__ index,
                                const float* __restrict__ Wsf,
                                const float* __restrict__ bsf,
                                int* __restrict__ bcursor,
                                uint2* __restrict__ pairs, int E, int B) {
    __shared__ int lcnt[BMAX];
    __shared__ int lbase[BMAX];
    int t = threadIdx.x;
    int base = blockIdx.x * K3_EPB;
    int nE = min(K3_EPB, E - base);

    for (int b = t; b < B; b += K3_TPB) lcnt[b] = 0;
    __syncthreads();

    // pass 1: count (cache idx in registers)
    int idxv[K3_EPT];
#pragma unroll
    for (int i = 0; i < K3_EPT; ++i) {
        int off = i * K3_TPB + t;
        idxv[i] = -1;
        if (off < nE) {
            idxv[i] = index[base + off];
            atomicAdd(&lcnt[idxv[i] >> BSH], 1);
        }
    }
    __syncthreads();

    // alloc global chunk per bucket; reset count for pass 2.
    // each bucket b is touched by exactly one thread (b mod 256 == t).
    for (int b = t; b < B; b += K3_TPB) {
        int c = lcnt[b];
        lbase[b] = (c > 0) ? atomicAdd(&bcursor[b], c) : 0;
        lcnt[b] = 0;
    }
    __syncthreads();

    // pass 2: compute score+exp, place pair
    float bsv = bsf[0];
#pragma unroll
    for (int i = 0; i < K3_EPT; ++i) {
        int off = i * K3_TPB + t;
        if (off >= nE) continue;
        int e = base + off;
        const float4* r = reinterpret_cast<const float4*>(ax + (size_t)e * DD);
        float s = bsv;
#pragma unroll
        for (int q = 0; q < 8; ++q) {
            float4 f = r[q];
            s = fmaf(f.x, Wsf[4 * q],     s);
            s = fmaf(f.y, Wsf[4 * q + 1], s);
            s = fmaf(f.z, Wsf[4 * q + 2], s);
            s = fmaf(f.w, Wsf[4 * q + 3], s);
        }
        float exv = __expf(s);
        int idx = idxv[i];
        int b = idx >> BSH;
        int pos = atomicAdd(&lcnt[b], 1);
        pairs[lbase[b] + pos] =
            make_uint2((unsigned)e | ((unsigned)(idx & (BNODES - 1)) << 21),
                       __float_as_uint(exv));
    }
}

// ---- K4: block per bucket — counting-sort chunk by node, register gather ----
__launch_bounds__(256)
__global__ void aggregate_kernel(const float* __restrict__ x,
                                 const uint2* __restrict__ pairs,
                                 const int* __restrict__ boff,
                                 const float* __restrict__ Wf,   // [DD][DD]
                                 const float* __restrict__ bfv,  // [DD]
                                 float* __restrict__ out, int N) {
    __shared__ uint2 sp[CHUNK];            // node-sorted pairs of current chunk
    __shared__ int cnt[BNODES];
    __shared__ int offs[BNODES + 1];
    __shared__ int cur[BNODES];

    int bk = blockIdx.x;
    int nbase = bk << BSH;
    int t = threadIdx.x;
    int wid = t >> 6;
    int lane = t & 63;
    int half = lane >> 5;
    int k = lane & 31;

    int beg = boff[bk], end = boff[bk + 1];

    float yacc[8], dacc[8];
#pragma unroll
    for (int s = 0; s < 8; ++s) { yacc[s] = 0.0f; dacc[s] = 0.0f; }

    for (int cb = beg; cb < end; cb += CHUNK) {
        int csz = min(CHUNK, end - cb);

        if (t < BNODES) cnt[t] = 0;
        __syncthreads();
        // count pass (coalesced global read; 1 LDS atomic per pair)
        for (int i = t; i < csz; i += 256)
            atomicAdd(&cnt[(pairs[cb + i].x >> 21) & (BNODES - 1)], 1);
        __syncthreads();
        // tiny serial scan
        if (t == 0) {
            int r = 0;
            for (int n = 0; n < BNODES; ++n) { offs[n] = r; cur[n] = r; r += cnt[n]; }
            offs[BNODES] = r;
        }
        __syncthreads();
        // place pass (1 LDS atomic per pair)
        for (int i = t; i < csz; i += 256) {
            uint2 pr = pairs[cb + i];
            int nl = (pr.x >> 21) & (BNODES - 1);
            int slot = atomicAdd(&cur[nl], 1);
            sp[slot] = pr;
        }
        __syncthreads();

        // register gather: wave wid owns nodes wid*8 .. wid*8+7
#pragma unroll
        for (int s = 0; s < 8; ++s) {
            int nl = wid * 8 + s;
            int lo = offs[nl], hi = offs[nl + 1];
            float ya = 0.0f, da = 0.0f;
            int p = lo + half;
            for (; p + 6 < hi; p += 8) {
                uint2 a0 = sp[p],     a1 = sp[p + 2];
                uint2 a2 = sp[p + 4], a3 = sp[p + 6];
                float w0 = __uint_as_float(a0.y);
                float w1 = __uint_as_float(a1.y);
                float w2 = __uint_as_float(a2.y);
                float w3 = __uint_as_float(a3.y);
                float x0 = x[(size_t)(a0.x & 0x1FFFFFu) * DD + k];
                float x1 = x[(size_t)(a1.x & 0x1FFFFFu) * DD + k];
                float x2 = x[(size_t)(a2.x & 0x1FFFFFu) * DD + k];
                float x3 = x[(size_t)(a3.x & 0x1FFFFFu) * DD + k];
                ya = fmaf(w0, x0, ya);
                ya = fmaf(w1, x1, ya);
                ya = fmaf(w2, x2, ya);
                ya = fmaf(w3, x3, ya);
                da += (w0 + w1) + (w2 + w3);
            }
            for (; p < hi; p += 2) {
                uint2 a = sp[p];
                float w = __uint_as_float(a.y);
                ya = fmaf(w, x[(size_t)(a.x & 0x1FFFFFu) * DD + k], ya);
                da += w;
            }
            yacc[s] += ya;
            dacc[s] += da;
        }
        __syncthreads();  // sp reused next chunk
    }

    // epilogue: combine halves, normalize, apply W, write
#pragma unroll
    for (int s = 0; s < 8; ++s) {
        float ya = yacc[s] + __shfl_xor(yacc[s], 32);
        float da = dacc[s] + __shfl_xor(dacc[s], 32);
        int node = nbase + wid * 8 + s;
        if (node < N) {
            float inv = 1.0f / (da + EPSF);
            float yn = ya * inv;
            float sw = da * inv;
            float o = sw * bfv[k];
#pragma unroll
            for (int kk = 0; kk < DD; ++kk)
                o = fmaf(__shfl(yn, kk), Wf[kk * DD + k], o);
            if (half == 0) out[(size_t)node * DD + k] = o;
        }
    }
}

extern "C" void kernel_launch(void* const* d_in, const int* in_sizes, int n_in,
                              void* d_out, int out_size, void* d_ws, size_t ws_size,
                              hipStream_t stream) {
    const float* x       = (const float*)d_in[0];
    const float* ax      = (const float*)d_in[1];
    const int*   index   = (const int*)d_in[2];
    // d_in[3] = size scalar; N derived from out_size
    const float* W_emb   = (const float*)d_in[4];
    const float* b_emb   = (const float*)d_in[5];
    const float* W_score = (const float*)d_in[6];
    const float* b_score = (const float*)d_in[7];

    int E = in_sizes[0] / DD;
    int N = out_size / DD;
    int B = (N + BNODES - 1) >> BSH;   // 1563 for N=50000 (<= BMAX)

    // workspace layout: pairs[E] (12.8 MB) + ~20 KB of counters.
    uint2* pairs   = (uint2*)d_ws;                    // [E]
    int*   bcnt    = (int*)(pairs + (size_t)E);       // [B]
    int*   boff    = bcnt + B;                        // [B+1]
    int*   bcursor = boff + B + 1;                    // [B]

    hipMemsetAsync(bcnt, 0, sizeof(int) * (size_t)B, stream);

    int blocksK = (E + K3_EPB - 1) / K3_EPB;
    hist_kernel<<<blocksK, K3_TPB, 0, stream>>>(index, bcnt, E, B);
    scan_kernel<<<1, SCAN_T, 0, stream>>>(bcnt, boff, bcursor, B);
    binscore_kernel<<<blocksK, K3_TPB, 0, stream>>>(ax, index, W_score, b_score,
                                                    bcursor, pairs, E, B);
    aggregate_kernel<<<B, 256, 0, stream>>>(x, pairs, boff, W_emb, b_emb,
                                            (float*)d_out, N);
}

// Round 11
// 198.318 us; speedup vs baseline: 2.3352x; 1.0538x over previous
//
#include <hip/hip_runtime.h>

#define DD 32
#define EPSF 1e-16f
#define SCAN_T 1024
#define BSH 5                    // 32 nodes per bucket
#define BNODES (1 << BSH)
#define BMAX 2048                // max buckets (N <= 65536)
#define K3_TPB 256
#define K3_EPT 16
#define K3_EPB (K3_TPB * K3_EPT) // 4096 edges per binning block
#define CHUNK 1536               // pairs per aggregate LDS chunk
#define CPT (CHUNK / 256)        // 6 pairs per thread per chunk
// NOTE: eid packed into 21 bits -> requires E < 2^21. E = 1.6M ok.

// ---- K0: per-edge score, pure streaming (2 edges/thread) ----
__global__ void score_kernel(const float* __restrict__ ax,
                             const float* __restrict__ Wsf,
                             const float* __restrict__ bsf,
                             float* __restrict__ ex, int E) {
    int i = blockIdx.x * blockDim.x + threadIdx.x;
    int e0 = i * 2;
    if (e0 >= E) return;
    bool two = (e0 + 1 < E);
    int e1 = two ? e0 + 1 : e0;

    const float4* r0 = reinterpret_cast<const float4*>(ax + (size_t)e0 * DD);
    const float4* r1 = reinterpret_cast<const float4*>(ax + (size_t)e1 * DD);
    float b = bsf[0];
    float s0 = b, s1 = b;
#pragma unroll
    for (int q = 0; q < 8; ++q) {
        float4 f0 = r0[q];
        float4 f1 = r1[q];
        float w0 = Wsf[4 * q], w1 = Wsf[4 * q + 1];
        float w2 = Wsf[4 * q + 2], w3 = Wsf[4 * q + 3];
        s0 = fmaf(f0.x, w0, s0); s0 = fmaf(f0.y, w1, s0);
        s0 = fmaf(f0.z, w2, s0); s0 = fmaf(f0.w, w3, s0);
        s1 = fmaf(f1.x, w0, s1); s1 = fmaf(f1.y, w1, s1);
        s1 = fmaf(f1.z, w2, s1); s1 = fmaf(f1.w, w3, s1);
    }
    float ex0 = __expf(s0), ex1 = __expf(s1);
    if (two) reinterpret_cast<float2*>(ex)[i] = make_float2(ex0, ex1);
    else     ex[e0] = ex0;
}

// ---- K1: block-local histogram of coarse buckets ----
__launch_bounds__(K3_TPB)
__global__ void hist_kernel(const int* __restrict__ index,
                            int* __restrict__ bcnt, int E, int B) {
    __shared__ int lcnt[BMAX];
    int t = threadIdx.x;
    int base = blockIdx.x * K3_EPB;
    int nE = min(K3_EPB, E - base);

    for (int b = t; b < B; b += K3_TPB) lcnt[b] = 0;
    __syncthreads();
    for (int off = t; off < nE; off += K3_TPB)
        atomicAdd(&lcnt[index[base + off] >> BSH], 1);
    __syncthreads();
    for (int b = t; b < B; b += K3_TPB)
        if (lcnt[b]) atomicAdd(&bcnt[b], lcnt[b]);
}

// ---- K2: exclusive scan of bcnt[B] -> boff[B+1], bcursor ----
__global__ void scan_kernel(const int* __restrict__ bcnt, int* __restrict__ boff,
                            int* __restrict__ bcursor, int B) {
    __shared__ int part[SCAN_T];
    int t = threadIdx.x;
    int chunk = (B + SCAN_T - 1) / SCAN_T;
    int lo = t * chunk;
    int hi = min(lo + chunk, B);
    int s = 0;
    for (int i = lo; i < hi; ++i) s += bcnt[i];
    part[t] = s;
    __syncthreads();
    for (int d = 1; d < SCAN_T; d <<= 1) {
        int v = (t >= d) ? part[t - d] : 0;
        __syncthreads();
        part[t] += v;
        __syncthreads();
    }
    int run = (t == 0) ? 0 : part[t - 1];
    for (int i = lo; i < hi; ++i) {
        boff[i] = run;
        bcursor[i] = run;
        run += bcnt[i];
    }
    if (t == SCAN_T - 1) boff[B] = run;  // == E
}

// ---- K3: two-pass bin; writes (eid|nloc) 4-byte tokens ----
__launch_bounds__(K3_TPB)
__global__ void bin_kernel(const int* __restrict__ index,
                           int* __restrict__ bcursor,
                           unsigned* __restrict__ pairs32, int E, int B) {
    __shared__ int lcnt[BMAX];
    __shared__ int lbase[BMAX];
    int t = threadIdx.x;
    int base = blockIdx.x * K3_EPB;
    int nE = min(K3_EPB, E - base);

    for (int b = t; b < B; b += K3_TPB) lcnt[b] = 0;
    __syncthreads();

    // pass 1: count (cache idx in registers)
    int idxv[K3_EPT];
#pragma unroll
    for (int i = 0; i < K3_EPT; ++i) {
        int off = i * K3_TPB + t;
        idxv[i] = -1;
        if (off < nE) {
            idxv[i] = index[base + off];
            atomicAdd(&lcnt[idxv[i] >> BSH], 1);
        }
    }
    __syncthreads();

    // alloc global chunk per bucket; reset count for pass 2.
    for (int b = t; b < B; b += K3_TPB) {
        int c = lcnt[b];
        lbase[b] = (c > 0) ? atomicAdd(&bcursor[b], c) : 0;
        lcnt[b] = 0;
    }
    __syncthreads();

    // pass 2: place token
#pragma unroll
    for (int i = 0; i < K3_EPT; ++i) {
        int off = i * K3_TPB + t;
        if (off >= nE) continue;
        int e = base + off;
        int idx = idxv[i];
        int b = idx >> BSH;
        int pos = atomicAdd(&lcnt[b], 1);
        pairs32[lbase[b] + pos] =
            (unsigned)e | ((unsigned)(idx & (BNODES - 1)) << 21);
    }
}

// ---- K4: block per bucket — counting-sort chunk by node, register gather ----
__launch_bounds__(256)
__global__ void aggregate_kernel(const float* __restrict__ x,
                                 const unsigned* __restrict__ pairs32,
                                 const float* __restrict__ ex,
                                 const int* __restrict__ boff,
                                 const float* __restrict__ Wf,   // [DD][DD]
                                 const float* __restrict__ bfv,  // [DD]
                                 float* __restrict__ out, int N) {
    __shared__ uint2 sp[CHUNK];            // node-sorted (token, ex) of chunk
    __shared__ int cnt[BNODES];
    __shared__ int offs[BNODES + 1];
    __shared__ int cur[BNODES];

    int bk = blockIdx.x;
    int nbase = bk << BSH;
    int t = threadIdx.x;
    int wid = t >> 6;
    int lane = t & 63;
    int half = lane >> 5;
    int k = lane & 31;

    int beg = boff[bk], end = boff[bk + 1];

    float yacc[8], dacc[8];
#pragma unroll
    for (int s = 0; s < 8; ++s) { yacc[s] = 0.0f; dacc[s] = 0.0f; }

    for (int cb = beg; cb < end; cb += CHUNK) {
        int csz = min(CHUNK, end - cb);

        // load tokens into regs; prefetch ex (latency hidden under count+scan)
        unsigned vreg[CPT];
        float exr[CPT];
#pragma unroll
        for (int j = 0; j < CPT; ++j) {
            int i = j * 256 + t;
            vreg[j] = 0xFFFFFFFFu;
            if (i < csz) {
                vreg[j] = pairs32[cb + i];
                exr[j] = ex[vreg[j] & 0x1FFFFFu];
            }
        }

        if (t < BNODES) cnt[t] = 0;
        __syncthreads();
#pragma unroll
        for (int j = 0; j < CPT; ++j)
            if (vreg[j] != 0xFFFFFFFFu)
                atomicAdd(&cnt[(vreg[j] >> 21) & (BNODES - 1)], 1);
        __syncthreads();
        if (t == 0) {
            int r = 0;
            for (int n = 0; n < BNODES; ++n) { offs[n] = r; cur[n] = r; r += cnt[n]; }
            offs[BNODES] = r;
        }
        __syncthreads();
#pragma unroll
        for (int j = 0; j < CPT; ++j) {
            if (vreg[j] != 0xFFFFFFFFu) {
                int nl = (vreg[j] >> 21) & (BNODES - 1);
                int slot = atomicAdd(&cur[nl], 1);
                sp[slot] = make_uint2(vreg[j], __float_as_uint(exr[j]));
            }
        }
        __syncthreads();

        // register gather: wave wid owns nodes wid*8 .. wid*8+7
#pragma unroll
        for (int s = 0; s < 8; ++s) {
            int nl = wid * 8 + s;
            int lo = offs[nl], hi = offs[nl + 1];
            float ya = 0.0f, da = 0.0f;
            int p = lo + half;
            for (; p + 6 < hi; p += 8) {
                uint2 a0 = sp[p],     a1 = sp[p + 2];
                uint2 a2 = sp[p + 4], a3 = sp[p + 6];
                float w0 = __uint_as_float(a0.y);
                float w1 = __uint_as_float(a1.y);
                float w2 = __uint_as_float(a2.y);
                float w3 = __uint_as_float(a3.y);
                float x0 = x[(size_t)(a0.x & 0x1FFFFFu) * DD + k];
                float x1 = x[(size_t)(a1.x & 0x1FFFFFu) * DD + k];
                float x2 = x[(size_t)(a2.x & 0x1FFFFFu) * DD + k];
                float x3 = x[(size_t)(a3.x & 0x1FFFFFu) * DD + k];
                ya = fmaf(w0, x0, ya);
                ya = fmaf(w1, x1, ya);
                ya = fmaf(w2, x2, ya);
                ya = fmaf(w3, x3, ya);
                da += (w0 + w1) + (w2 + w3);
            }
            for (; p < hi; p += 2) {
                uint2 a = sp[p];
                float w = __uint_as_float(a.y);
                ya = fmaf(w, x[(size_t)(a.x & 0x1FFFFFu) * DD + k], ya);
                da += w;
            }
            yacc[s] += ya;
            dacc[s] += da;
        }
        __syncthreads();  // sp reused next chunk
    }

    // epilogue: combine halves, normalize, apply W, write
#pragma unroll
    for (int s = 0; s < 8; ++s) {
        float ya = yacc[s] + __shfl_xor(yacc[s], 32);
        float da = dacc[s] + __shfl_xor(dacc[s], 32);
        int node = nbase + wid * 8 + s;
        if (node < N) {
            float inv = 1.0f / (da + EPSF);
            float yn = ya * inv;
            float sw = da * inv;
            float o = sw * bfv[k];
#pragma unroll
            for (int kk = 0; kk < DD; ++kk)
                o = fmaf(__shfl(yn, kk), Wf[kk * DD + k], o);
            if (half == 0) out[(size_t)node * DD + k] = o;
        }
    }
}

extern "C" void kernel_launch(void* const* d_in, const int* in_sizes, int n_in,
                              void* d_out, int out_size, void* d_ws, size_t ws_size,
                              hipStream_t stream) {
    const float* x       = (const float*)d_in[0];
    const float* ax      = (const float*)d_in[1];
    const int*   index   = (const int*)d_in[2];
    // d_in[3] = size scalar; N derived from out_size
    const float* W_emb   = (const float*)d_in[4];
    const float* b_emb   = (const float*)d_in[5];
    const float* W_score = (const float*)d_in[6];
    const float* b_score = (const float*)d_in[7];

    int E = in_sizes[0] / DD;
    int N = out_size / DD;
    int B = (N + BNODES - 1) >> BSH;   // 1563 for N=50000 (<= BMAX)

    // workspace: pairs32[E] 6.4 MB + ex[E] 6.4 MB + ~20 KB counters = 12.8 MB
    unsigned* pairs32 = (unsigned*)d_ws;                 // [E]
    float*    ex      = (float*)(pairs32 + (size_t)E);   // [E]
    int*      bcnt    = (int*)(ex + (size_t)E);          // [B]
    int*      boff    = bcnt + B;                        // [B+1]
    int*      bcursor = boff + B + 1;                    // [B]

    hipMemsetAsync(bcnt, 0, sizeof(int) * (size_t)B, stream);

    int blocksE2 = ((E + 1) / 2 + 255) / 256;
    score_kernel<<<blocksE2, 256, 0, stream>>>(ax, W_score, b_score, ex, E);

    int blocksK = (E + K3_EPB - 1) / K3_EPB;
    hist_kernel<<<blocksK, K3_TPB, 0, stream>>>(index, bcnt, E, B);
    scan_kernel<<<1, SCAN_T, 0, stream>>>(bcnt, boff, bcursor, B);
    bin_kernel<<<blocksK, K3_TPB, 0, stream>>>(index, bcursor, pairs32, E, B);
    aggregate_kernel<<<B, 256, 0, stream>>>(x, pairs32, ex, boff, W_emb, b_emb,
                                            (float*)d_out, N);
}

// Round 12
// 195.294 us; speedup vs baseline: 2.3713x; 1.0155x over previous
//
#include <hip/hip_runtime.h>

#define DD 32
#define EPSF 1e-16f
#define SCAN_T 1024
#define BSH 5                    // 32 nodes per bucket
#define BNODES (1 << BSH)
#define BMAX 2048                // max buckets (N <= 65536)
#define K3_TPB 256
#define K3_EPT 16
#define K3_EPB (K3_TPB * K3_EPT) // 4096 edges per binning block
#define CHUNK 1536               // pairs per aggregate LDS chunk
#define CPT (CHUNK / 256)        // 6 pairs per thread per chunk
// NOTE: eid packed into 21 bits -> requires E < 2^21. E = 1.6M ok.

// ---- K0: per-edge score, pure streaming (2 edges/thread) ----
__global__ void score_kernel(const float* __restrict__ ax,
                             const float* __restrict__ Wsf,
                             const float* __restrict__ bsf,
                             float* __restrict__ ex, int E) {
    int i = blockIdx.x * blockDim.x + threadIdx.x;
    int e0 = i * 2;
    if (e0 >= E) return;
    bool two = (e0 + 1 < E);
    int e1 = two ? e0 + 1 : e0;

    const float4* r0 = reinterpret_cast<const float4*>(ax + (size_t)e0 * DD);
    const float4* r1 = reinterpret_cast<const float4*>(ax + (size_t)e1 * DD);
    float b = bsf[0];
    float s0 = b, s1 = b;
#pragma unroll
    for (int q = 0; q < 8; ++q) {
        float4 f0 = r0[q];
        float4 f1 = r1[q];
        float w0 = Wsf[4 * q], w1 = Wsf[4 * q + 1];
        float w2 = Wsf[4 * q + 2], w3 = Wsf[4 * q + 3];
        s0 = fmaf(f0.x, w0, s0); s0 = fmaf(f0.y, w1, s0);
        s0 = fmaf(f0.z, w2, s0); s0 = fmaf(f0.w, w3, s0);
        s1 = fmaf(f1.x, w0, s1); s1 = fmaf(f1.y, w1, s1);
        s1 = fmaf(f1.z, w2, s1); s1 = fmaf(f1.w, w3, s1);
    }
    float ex0 = __expf(s0), ex1 = __expf(s1);
    if (two) reinterpret_cast<float2*>(ex)[i] = make_float2(ex0, ex1);
    else     ex[e0] = ex0;
}

// ---- K1: block-local histogram of coarse buckets ----
__launch_bounds__(K3_TPB)
__global__ void hist_kernel(const int* __restrict__ index,
                            int* __restrict__ bcnt, int E, int B) {
    __shared__ int lcnt[BMAX];
    int t = threadIdx.x;
    int base = blockIdx.x * K3_EPB;
    int nE = min(K3_EPB, E - base);

    for (int b = t; b < B; b += K3_TPB) lcnt[b] = 0;
    __syncthreads();
    for (int off = t; off < nE; off += K3_TPB)
        atomicAdd(&lcnt[index[base + off] >> BSH], 1);
    __syncthreads();
    for (int b = t; b < B; b += K3_TPB)
        if (lcnt[b]) atomicAdd(&bcnt[b], lcnt[b]);
}

// ---- K2: exclusive scan of bcnt[B] -> boff[B+1], bcursor ----
__global__ void scan_kernel(const int* __restrict__ bcnt, int* __restrict__ boff,
                            int* __restrict__ bcursor, int B) {
    __shared__ int part[SCAN_T];
    int t = threadIdx.x;
    int chunk = (B + SCAN_T - 1) / SCAN_T;
    int lo = t * chunk;
    int hi = min(lo + chunk, B);
    int s = 0;
    for (int i = lo; i < hi; ++i) s += bcnt[i];
    part[t] = s;
    __syncthreads();
    for (int d = 1; d < SCAN_T; d <<= 1) {
        int v = (t >= d) ? part[t - d] : 0;
        __syncthreads();
        part[t] += v;
        __syncthreads();
    }
    int run = (t == 0) ? 0 : part[t - 1];
    for (int i = lo; i < hi; ++i) {
        boff[i] = run;
        bcursor[i] = run;
        run += bcnt[i];
    }
    if (t == SCAN_T - 1) boff[B] = run;  // == E
}

// ---- K3: two-pass bin; writes (eid|nloc, ex) uint2 pairs ----
__launch_bounds__(K3_TPB)
__global__ void bin_kernel(const int* __restrict__ index,
                           const float* __restrict__ ex,
                           int* __restrict__ bcursor,
                           uint2* __restrict__ pairs, int E, int B) {
    __shared__ int lcnt[BMAX];
    __shared__ int lbase[BMAX];
    int t = threadIdx.x;
    int base = blockIdx.x * K3_EPB;
    int nE = min(K3_EPB, E - base);

    for (int b = t; b < B; b += K3_TPB) lcnt[b] = 0;
    __syncthreads();

    // pass 1: count (cache idx in registers)
    int idxv[K3_EPT];
#pragma unroll
    for (int i = 0; i < K3_EPT; ++i) {
        int off = i * K3_TPB + t;
        idxv[i] = -1;
        if (off < nE) {
            idxv[i] = index[base + off];
            atomicAdd(&lcnt[idxv[i] >> BSH], 1);
        }
    }
    __syncthreads();

    // alloc global chunk per bucket; reset count for pass 2.
    // each bucket b is touched by exactly one thread (b mod 256 == t).
    for (int b = t; b < B; b += K3_TPB) {
        int c = lcnt[b];
        lbase[b] = (c > 0) ? atomicAdd(&bcursor[b], c) : 0;
        lcnt[b] = 0;
    }
    __syncthreads();

    // pass 2: place (token, ex) — ex read is coalesced (sequential e)
#pragma unroll
    for (int i = 0; i < K3_EPT; ++i) {
        int off = i * K3_TPB + t;
        if (off >= nE) continue;
        int e = base + off;
        float exv = ex[e];
        int idx = idxv[i];
        int b = idx >> BSH;
        int pos = atomicAdd(&lcnt[b], 1);
        pairs[lbase[b] + pos] =
            make_uint2((unsigned)e | ((unsigned)(idx & (BNODES - 1)) << 21),
                       __float_as_uint(exv));
    }
}

// ---- K4: block per bucket — counting-sort chunk by node, register gather ----
__launch_bounds__(256)
__global__ void aggregate_kernel(const float* __restrict__ x,
                                 const uint2* __restrict__ pairs,
                                 const int* __restrict__ boff,
                                 const float* __restrict__ Wf,   // [DD][DD]
                                 const float* __restrict__ bfv,  // [DD]
                                 float* __restrict__ out, int N) {
    __shared__ uint2 sp[CHUNK];            // node-sorted (token, ex) of chunk
    __shared__ int cnt[BNODES];
    __shared__ int offs[BNODES + 1];
    __shared__ int cur[BNODES];

    int bk = blockIdx.x;
    int nbase = bk << BSH;
    int t = threadIdx.x;
    int wid = t >> 6;
    int lane = t & 63;
    int half = lane >> 5;
    int k = lane & 31;

    int beg = boff[bk], end = boff[bk + 1];

    float yacc[8], dacc[8];
#pragma unroll
    for (int s = 0; s < 8; ++s) { yacc[s] = 0.0f; dacc[s] = 0.0f; }

    for (int cb = beg; cb < end; cb += CHUNK) {
        int csz = min(CHUNK, end - cb);

        // coalesced load of this chunk's pairs into registers
        uint2 vreg[CPT];
#pragma unroll
        for (int j = 0; j < CPT; ++j) {
            int i = j * 256 + t;
            vreg[j].x = 0xFFFFFFFFu;
            if (i < csz) vreg[j] = pairs[cb + i];
        }

        if (t < BNODES) cnt[t] = 0;
        __syncthreads();
#pragma unroll
        for (int j = 0; j < CPT; ++j)
            if (vreg[j].x != 0xFFFFFFFFu)
                atomicAdd(&cnt[(vreg[j].x >> 21) & (BNODES - 1)], 1);
        __syncthreads();
        if (t == 0) {
            int r = 0;
            for (int n = 0; n < BNODES; ++n) { offs[n] = r; cur[n] = r; r += cnt[n]; }
            offs[BNODES] = r;
        }
        __syncthreads();
#pragma unroll
        for (int j = 0; j < CPT; ++j) {
            if (vreg[j].x != 0xFFFFFFFFu) {
                int nl = (vreg[j].x >> 21) & (BNODES - 1);
                int slot = atomicAdd(&cur[nl], 1);
                sp[slot] = vreg[j];
            }
        }
        __syncthreads();

        // register gather: wave wid owns nodes wid*8 .. wid*8+7
#pragma unroll
        for (int s = 0; s < 8; ++s) {
            int nl = wid * 8 + s;
            int lo = offs[nl], hi = offs[nl + 1];
            float ya = 0.0f, da = 0.0f;
            int p = lo + half;
            for (; p + 6 < hi; p += 8) {
                uint2 a0 = sp[p],     a1 = sp[p + 2];
                uint2 a2 = sp[p + 4], a3 = sp[p + 6];
                float w0 = __uint_as_float(a0.y);
                float w1 = __uint_as_float(a1.y);
                float w2 = __uint_as_float(a2.y);
                float w3 = __uint_as_float(a3.y);
                float x0 = x[(size_t)(a0.x & 0x1FFFFFu) * DD + k];
                float x1 = x[(size_t)(a1.x & 0x1FFFFFu) * DD + k];
                float x2 = x[(size_t)(a2.x & 0x1FFFFFu) * DD + k];
                float x3 = x[(size_t)(a3.x & 0x1FFFFFu) * DD + k];
                ya = fmaf(w0, x0, ya);
                ya = fmaf(w1, x1, ya);
                ya = fmaf(w2, x2, ya);
                ya = fmaf(w3, x3, ya);
                da += (w0 + w1) + (w2 + w3);
            }
            for (; p < hi; p += 2) {
                uint2 a = sp[p];
                float w = __uint_as_float(a.y);
                ya = fmaf(w, x[(size_t)(a.x & 0x1FFFFFu) * DD + k], ya);
                da += w;
            }
            yacc[s] += ya;
            dacc[s] += da;
        }
        __syncthreads();  // sp reused next chunk
    }

    // epilogue: combine halves, normalize, apply W, write
#pragma unroll
    for (int s = 0; s < 8; ++s) {
        float ya = yacc[s] + __shfl_xor(yacc[s], 32);
        float da = dacc[s] + __shfl_xor(dacc[s], 32);
        int node = nbase + wid * 8 + s;
        if (node < N) {
            float inv = 1.0f / (da + EPSF);
            float yn = ya * inv;
            float sw = da * inv;
            float o = sw * bfv[k];
#pragma unroll
            for (int kk = 0; kk < DD; ++kk)
                o = fmaf(__shfl(yn, kk), Wf[kk * DD + k], o);
            if (half == 0) out[(size_t)node * DD + k] = o;
        }
    }
}

extern "C" void kernel_launch(void* const* d_in, const int* in_sizes, int n_in,
                              void* d_out, int out_size, void* d_ws, size_t ws_size,
                              hipStream_t stream) {
    const float* x       = (const float*)d_in[0];
    const float* ax      = (const float*)d_in[1];
    const int*   index   = (const int*)d_in[2];
    // d_in[3] = size scalar; N derived from out_size
    const float* W_emb   = (const float*)d_in[4];
    const float* b_emb   = (const float*)d_in[5];
    const float* W_score = (const float*)d_in[6];
    const float* b_score = (const float*)d_in[7];

    int E = in_sizes[0] / DD;
    int N = out_size / DD;
    int B = (N + BNODES - 1) >> BSH;   // 1563 for N=50000 (<= BMAX)

    // workspace: pairs[E] 12.8 MB + ex[E] 6.4 MB + ~20 KB counters (ws ~800 MB)
    uint2* pairs   = (uint2*)d_ws;                    // [E]
    float* ex      = (float*)(pairs + (size_t)E);     // [E]
    int*   bcnt    = (int*)(ex + (size_t)E);          // [B]
    int*   boff    = bcnt + B;                        // [B+1]
    int*   bcursor = boff + B + 1;                    // [B]

    hipMemsetAsync(bcnt, 0, sizeof(int) * (size_t)B, stream);

    int blocksE2 = ((E + 1) / 2 + 255) / 256;
    score_kernel<<<blocksE2, 256, 0, stream>>>(ax, W_score, b_score, ex, E);

    int blocksK = (E + K3_EPB - 1) / K3_EPB;
    hist_kernel<<<blocksK, K3_TPB, 0, stream>>>(index, bcnt, E, B);
    scan_kernel<<<1, SCAN_T, 0, stream>>>(bcnt, boff, bcursor, B);
    bin_kernel<<<blocksK, K3_TPB, 0, stream>>>(index, ex, bcursor, pairs, E, B);
    aggregate_kernel<<<B, 256, 0, stream>>>(x, pairs, boff, W_emb, b_emb,
                                            (float*)d_out, N);
}

// Round 13
// 194.051 us; speedup vs baseline: 2.3865x; 1.0064x over previous
//
#include <hip/hip_runtime.h>

#define DD 32
#define EPSF 1e-16f
#define SCAN_T 1024
#define BSH 5                    // 32 nodes per bucket
#define BNODES (1 << BSH)
#define BMAX 2048                // max buckets (N <= 65536)
#define H_TPB 256
#define K3_TPB 1024
#define K3_EPT 4
#define K3_EPB (K3_TPB * K3_EPT) // 4096 edges per binning block
#define CHUNK 1536               // pairs per aggregate LDS chunk
#define CPT (CHUNK / 256)        // 6 pairs per thread per chunk
// NOTE: eid packed into 21 bits -> requires E < 2^21. E = 1.6M ok.

// ---- K1: block-local histogram of coarse buckets ----
__launch_bounds__(H_TPB)
__global__ void hist_kernel(const int* __restrict__ index,
                            int* __restrict__ bcnt, int E, int B) {
    __shared__ int lcnt[BMAX];
    int t = threadIdx.x;
    int base = blockIdx.x * K3_EPB;
    int nE = min(K3_EPB, E - base);

    for (int b = t; b < B; b += H_TPB) lcnt[b] = 0;
    __syncthreads();
    for (int off = t; off < nE; off += H_TPB)
        atomicAdd(&lcnt[index[base + off] >> BSH], 1);
    __syncthreads();
    for (int b = t; b < B; b += H_TPB)
        if (lcnt[b]) atomicAdd(&bcnt[b], lcnt[b]);
}

// ---- K2: exclusive scan of bcnt[B] -> boff[B+1], bcursor ----
__global__ void scan_kernel(const int* __restrict__ bcnt, int* __restrict__ boff,
                            int* __restrict__ bcursor, int B) {
    __shared__ int part[SCAN_T];
    int t = threadIdx.x;
    int chunk = (B + SCAN_T - 1) / SCAN_T;
    int lo = t * chunk;
    int hi = min(lo + chunk, B);
    int s = 0;
    for (int i = lo; i < hi; ++i) s += bcnt[i];
    part[t] = s;
    __syncthreads();
    for (int d = 1; d < SCAN_T; d <<= 1) {
        int v = (t >= d) ? part[t - d] : 0;
        __syncthreads();
        part[t] += v;
        __syncthreads();
    }
    int run = (t == 0) ? 0 : part[t - 1];
    for (int i = lo; i < hi; ++i) {
        boff[i] = run;
        bcursor[i] = run;
        run += bcnt[i];
    }
    if (t == SCAN_T - 1) boff[B] = run;  // == E
}

// ---- K3: fused score + two-pass bin; 1024 threads x 4 edges ----
__launch_bounds__(K3_TPB)
__global__ void binscore_kernel(const float* __restrict__ ax,
                                const int* __restrict__ index,
                                const float* __restrict__ Wsf,
                                const float* __restrict__ bsf,
                                int* __restrict__ bcursor,
                                uint2* __restrict__ pairs, int E, int B) {
    __shared__ int lcnt[BMAX];
    __shared__ int lbase[BMAX];
    int t = threadIdx.x;
    int base = blockIdx.x * K3_EPB;
    int nE = min(K3_EPB, E - base);

    for (int b = t; b < B; b += K3_TPB) lcnt[b] = 0;
    __syncthreads();

    // pass 1: count (cache idx in registers)
    int idxv[K3_EPT];
#pragma unroll
    for (int i = 0; i < K3_EPT; ++i) {
        int off = i * K3_TPB + t;
        idxv[i] = -1;
        if (off < nE) {
            idxv[i] = index[base + off];
            atomicAdd(&lcnt[idxv[i] >> BSH], 1);
        }
    }
    __syncthreads();

    // alloc global chunk per bucket; reset count for pass 2.
    // each bucket b is touched by exactly one thread (b mod 1024 == t).
    for (int b = t; b < B; b += K3_TPB) {
        int c = lcnt[b];
        lbase[b] = (c > 0) ? atomicAdd(&bcursor[b], c) : 0;
        lcnt[b] = 0;
    }
    __syncthreads();

    // pass 2: compute score+exp, place (token, ex)
    float bsv = bsf[0];
#pragma unroll
    for (int i = 0; i < K3_EPT; ++i) {
        int off = i * K3_TPB + t;
        if (off >= nE) continue;
        int e = base + off;
        const float4* r = reinterpret_cast<const float4*>(ax + (size_t)e * DD);
        float s = bsv;
#pragma unroll
        for (int q = 0; q < 8; ++q) {
            float4 f = r[q];
            s = fmaf(f.x, Wsf[4 * q],     s);
            s = fmaf(f.y, Wsf[4 * q + 1], s);
            s = fmaf(f.z, Wsf[4 * q + 2], s);
            s = fmaf(f.w, Wsf[4 * q + 3], s);
        }
        float exv = __expf(s);
        int idx = idxv[i];
        int b = idx >> BSH;
        int pos = atomicAdd(&lcnt[b], 1);
        pairs[lbase[b] + pos] =
            make_uint2((unsigned)e | ((unsigned)(idx & (BNODES - 1)) << 21),
                       __float_as_uint(exv));
    }
}

// ---- K4: block per bucket — counting-sort chunk by node, register gather ----
__launch_bounds__(256)
__global__ void aggregate_kernel(const float* __restrict__ x,
                                 const uint2* __restrict__ pairs,
                                 const int* __restrict__ boff,
                                 const float* __restrict__ Wf,   // [DD][DD]
                                 const float* __restrict__ bfv,  // [DD]
                                 float* __restrict__ out, int N) {
    __shared__ uint2 sp[CHUNK];            // node-sorted (token, ex) of chunk
    __shared__ int cnt[BNODES];
    __shared__ int offs[BNODES + 1];
    __shared__ int cur[BNODES];

    int bk = blockIdx.x;
    int nbase = bk << BSH;
    int t = threadIdx.x;
    int wid = t >> 6;
    int lane = t & 63;
    int half = lane >> 5;
    int k = lane & 31;

    int beg = boff[bk], end = boff[bk + 1];

    float yacc[8], dacc[8];
#pragma unroll
    for (int s = 0; s < 8; ++s) { yacc[s] = 0.0f; dacc[s] = 0.0f; }

    for (int cb = beg; cb < end; cb += CHUNK) {
        int csz = min(CHUNK, end - cb);

        // coalesced load of this chunk's pairs into registers
        uint2 vreg[CPT];
#pragma unroll
        for (int j = 0; j < CPT; ++j) {
            int i = j * 256 + t;
            vreg[j].x = 0xFFFFFFFFu;
            if (i < csz) vreg[j] = pairs[cb + i];
        }

        if (t < BNODES) cnt[t] = 0;
        __syncthreads();
#pragma unroll
        for (int j = 0; j < CPT; ++j)
            if (vreg[j].x != 0xFFFFFFFFu)
                atomicAdd(&cnt[(vreg[j].x >> 21) & (BNODES - 1)], 1);
        __syncthreads();
        if (t == 0) {
            int r = 0;
            for (int n = 0; n < BNODES; ++n) { offs[n] = r; cur[n] = r; r += cnt[n]; }
            offs[BNODES] = r;
        }
        __syncthreads();
#pragma unroll
        for (int j = 0; j < CPT; ++j) {
            if (vreg[j].x != 0xFFFFFFFFu) {
                int nl = (vreg[j].x >> 21) & (BNODES - 1);
                int slot = atomicAdd(&cur[nl], 1);
                sp[slot] = vreg[j];
            }
        }
        __syncthreads();

        // register gather: wave wid owns nodes wid*8 .. wid*8+7
        // 8 x-rows in flight per half-wave (16 per wave)
#pragma unroll
        for (int s = 0; s < 8; ++s) {
            int nl = wid * 8 + s;
            int lo = offs[nl], hi = offs[nl + 1];
            float ya = 0.0f, da = 0.0f;
            int p = lo + half;
            for (; p + 14 < hi; p += 16) {
                uint2 a0 = sp[p],      a1 = sp[p + 2];
                uint2 a2 = sp[p + 4],  a3 = sp[p + 6];
                uint2 a4 = sp[p + 8],  a5 = sp[p + 10];
                uint2 a6 = sp[p + 12], a7 = sp[p + 14];
                float w0 = __uint_as_float(a0.y), w1 = __uint_as_float(a1.y);
                float w2 = __uint_as_float(a2.y), w3 = __uint_as_float(a3.y);
                float w4 = __uint_as_float(a4.y), w5 = __uint_as_float(a5.y);
                float w6 = __uint_as_float(a6.y), w7 = __uint_as_float(a7.y);
                float x0 = x[(size_t)(a0.x & 0x1FFFFFu) * DD + k];
                float x1 = x[(size_t)(a1.x & 0x1FFFFFu) * DD + k];
                float x2 = x[(size_t)(a2.x & 0x1FFFFFu) * DD + k];
                float x3 = x[(size_t)(a3.x & 0x1FFFFFu) * DD + k];
                float x4 = x[(size_t)(a4.x & 0x1FFFFFu) * DD + k];
                float x5 = x[(size_t)(a5.x & 0x1FFFFFu) * DD + k];
                float x6 = x[(size_t)(a6.x & 0x1FFFFFu) * DD + k];
                float x7 = x[(size_t)(a7.x & 0x1FFFFFu) * DD + k];
                ya = fmaf(w0, x0, ya); ya = fmaf(w1, x1, ya);
                ya = fmaf(w2, x2, ya); ya = fmaf(w3, x3, ya);
                ya = fmaf(w4, x4, ya); ya = fmaf(w5, x5, ya);
                ya = fmaf(w6, x6, ya); ya = fmaf(w7, x7, ya);
                da += ((w0 + w1) + (w2 + w3)) + ((w4 + w5) + (w6 + w7));
            }
            for (; p + 6 < hi; p += 8) {
                uint2 a0 = sp[p],     a1 = sp[p + 2];
                uint2 a2 = sp[p + 4], a3 = sp[p + 6];
                float w0 = __uint_as_float(a0.y), w1 = __uint_as_float(a1.y);
                float w2 = __uint_as_float(a2.y), w3 = __uint_as_float(a3.y);
                float x0 = x[(size_t)(a0.x & 0x1FFFFFu) * DD + k];
                float x1 = x[(size_t)(a1.x & 0x1FFFFFu) * DD + k];
                float x2 = x[(size_t)(a2.x & 0x1FFFFFu) * DD + k];
                float x3 = x[(size_t)(a3.x & 0x1FFFFFu) * DD + k];
                ya = fmaf(w0, x0, ya); ya = fmaf(w1, x1, ya);
                ya = fmaf(w2, x2, ya); ya = fmaf(w3, x3, ya);
                da += (w0 + w1) + (w2 + w3);
            }
            for (; p < hi; p += 2) {
                uint2 a = sp[p];
                float w = __uint_as_float(a.y);
                ya = fmaf(w, x[(size_t)(a.x & 0x1FFFFFu) * DD + k], ya);
                da += w;
            }
            yacc[s] += ya;
            dacc[s] += da;
        }
        __syncthreads();  // sp reused next chunk
    }

    // epilogue: combine halves, normalize, apply W, write
#pragma unroll
    for (int s = 0; s < 8; ++s) {
        float ya = yacc[s] + __shfl_xor(yacc[s], 32);
        float da = dacc[s] + __shfl_xor(dacc[s], 32);
        int node = nbase + wid * 8 + s;
        if (node < N) {
            float inv = 1.0f / (da + EPSF);
            float yn = ya * inv;
            float sw = da * inv;
            float o = sw * bfv[k];
#pragma unroll
            for (int kk = 0; kk < DD; ++kk)
                o = fmaf(__shfl(yn, kk), Wf[kk * DD + k], o);
            if (half == 0) out[(size_t)node * DD + k] = o;
        }
    }
}

extern "C" void kernel_launch(void* const* d_in, const int* in_sizes, int n_in,
                              void* d_out, int out_size, void* d_ws, size_t ws_size,
                              hipStream_t stream) {
    const float* x       = (const float*)d_in[0];
    const float* ax      = (const float*)d_in[1];
    const int*   index   = (const int*)d_in[2];
    // d_in[3] = size scalar; N derived from out_size
    const float* W_emb   = (const float*)d_in[4];
    const float* b_emb   = (const float*)d_in[5];
    const float* W_score = (const float*)d_in[6];
    const float* b_score = (const float*)d_in[7];

    int E = in_sizes[0] / DD;
    int N = out_size / DD;
    int B = (N + BNODES - 1) >> BSH;   // 1563 for N=50000 (<= BMAX)

    // workspace: pairs[E] 12.8 MB + ~20 KB counters (ws ~800 MB)
    uint2* pairs   = (uint2*)d_ws;                    // [E]
    int*   bcnt    = (int*)(pairs + (size_t)E);       // [B]
    int*   boff    = bcnt + B;                        // [B+1]
    int*   bcursor = boff + B + 1;                    // [B]

    hipMemsetAsync(bcnt, 0, sizeof(int) * (size_t)B, stream);

    int blocksK = (E + K3_EPB - 1) / K3_EPB;
    hist_kernel<<<blocksK, H_TPB, 0, stream>>>(index, bcnt, E, B);
    scan_kernel<<<1, SCAN_T, 0, stream>>>(bcnt, boff, bcursor, B);
    binscore_kernel<<<blocksK, K3_TPB, 0, stream>>>(ax, index, W_score, b_score,
                                                    bcursor, pairs, E, B);
    aggregate_kernel<<<B, 256, 0, stream>>>(x, pairs, boff, W_emb, b_emb,
                                            (float*)d_out, N);
}

// Round 14
// 184.636 us; speedup vs baseline: 2.5082x; 1.0510x over previous
//
#include <hip/hip_runtime.h>

#define DD 32
#define EPSF 1e-16f
#define SCAN_T 1024
#define BSH 5                    // 32 nodes per bucket
#define BNODES (1 << BSH)
#define BMAX 2048                // max buckets (N <= 65536)
#define K3_TPB 256
#define K3_EPT 16
#define K3_EPB (K3_TPB * K3_EPT) // 4096 edges per binning block
#define CHUNK 1536               // pairs per aggregate LDS chunk
#define CPT (CHUNK / 256)        // 6 pairs per thread per chunk
// NOTE: eid packed into 21 bits -> requires E < 2^21. E = 1.6M ok.

// ---- K0: per-edge score, pure streaming (2 edges/thread) ----
__global__ void score_kernel(const float* __restrict__ ax,
                             const float* __restrict__ Wsf,
                             const float* __restrict__ bsf,
                             float* __restrict__ ex, int E) {
    int i = blockIdx.x * blockDim.x + threadIdx.x;
    int e0 = i * 2;
    if (e0 >= E) return;
    bool two = (e0 + 1 < E);
    int e1 = two ? e0 + 1 : e0;

    const float4* r0 = reinterpret_cast<const float4*>(ax + (size_t)e0 * DD);
    const float4* r1 = reinterpret_cast<const float4*>(ax + (size_t)e1 * DD);
    float b = bsf[0];
    float s0 = b, s1 = b;
#pragma unroll
    for (int q = 0; q < 8; ++q) {
        float4 f0 = r0[q];
        float4 f1 = r1[q];
        float w0 = Wsf[4 * q], w1 = Wsf[4 * q + 1];
        float w2 = Wsf[4 * q + 2], w3 = Wsf[4 * q + 3];
        s0 = fmaf(f0.x, w0, s0); s0 = fmaf(f0.y, w1, s0);
        s0 = fmaf(f0.z, w2, s0); s0 = fmaf(f0.w, w3, s0);
        s1 = fmaf(f1.x, w0, s1); s1 = fmaf(f1.y, w1, s1);
        s1 = fmaf(f1.z, w2, s1); s1 = fmaf(f1.w, w3, s1);
    }
    float ex0 = __expf(s0), ex1 = __expf(s1);
    if (two) reinterpret_cast<float2*>(ex)[i] = make_float2(ex0, ex1);
    else     ex[e0] = ex0;
}

// ---- K1: block-local histogram of coarse buckets ----
__launch_bounds__(K3_TPB)
__global__ void hist_kernel(const int* __restrict__ index,
                            int* __restrict__ bcnt, int E, int B) {
    __shared__ int lcnt[BMAX];
    int t = threadIdx.x;
    int base = blockIdx.x * K3_EPB;
    int nE = min(K3_EPB, E - base);

    for (int b = t; b < B; b += K3_TPB) lcnt[b] = 0;
    __syncthreads();
    for (int off = t; off < nE; off += K3_TPB)
        atomicAdd(&lcnt[index[base + off] >> BSH], 1);
    __syncthreads();
    for (int b = t; b < B; b += K3_TPB)
        if (lcnt[b]) atomicAdd(&bcnt[b], lcnt[b]);
}

// ---- K2: exclusive scan of bcnt[B] -> boff[B+1], bcursor ----
__global__ void scan_kernel(const int* __restrict__ bcnt, int* __restrict__ boff,
                            int* __restrict__ bcursor, int B) {
    __shared__ int part[SCAN_T];
    int t = threadIdx.x;
    int chunk = (B + SCAN_T - 1) / SCAN_T;
    int lo = t * chunk;
    int hi = min(lo + chunk, B);
    int s = 0;
    for (int i = lo; i < hi; ++i) s += bcnt[i];
    part[t] = s;
    __syncthreads();
    for (int d = 1; d < SCAN_T; d <<= 1) {
        int v = (t >= d) ? part[t - d] : 0;
        __syncthreads();
        part[t] += v;
        __syncthreads();
    }
    int run = (t == 0) ? 0 : part[t - 1];
    for (int i = lo; i < hi; ++i) {
        boff[i] = run;
        bcursor[i] = run;
        run += bcnt[i];
    }
    if (t == SCAN_T - 1) boff[B] = run;  // == E
}

// ---- K3: two-pass bin; writes (eid|nloc, ex) uint2 pairs ----
__launch_bounds__(K3_TPB)
__global__ void bin_kernel(const int* __restrict__ index,
                           const float* __restrict__ ex,
                           int* __restrict__ bcursor,
                           uint2* __restrict__ pairs, int E, int B) {
    __shared__ int lcnt[BMAX];
    __shared__ int lbase[BMAX];
    int t = threadIdx.x;
    int base = blockIdx.x * K3_EPB;
    int nE = min(K3_EPB, E - base);

    for (int b = t; b < B; b += K3_TPB) lcnt[b] = 0;
    __syncthreads();

    // pass 1: count (cache idx in registers)
    int idxv[K3_EPT];
#pragma unroll
    for (int i = 0; i < K3_EPT; ++i) {
        int off = i * K3_TPB + t;
        idxv[i] = -1;
        if (off < nE) {
            idxv[i] = index[base + off];
            atomicAdd(&lcnt[idxv[i] >> BSH], 1);
        }
    }
    __syncthreads();

    // alloc global chunk per bucket; reset count for pass 2.
    // each bucket b is touched by exactly one thread (b mod 256 == t).
    for (int b = t; b < B; b += K3_TPB) {
        int c = lcnt[b];
        lbase[b] = (c > 0) ? atomicAdd(&bcursor[b], c) : 0;
        lcnt[b] = 0;
    }
    __syncthreads();

    // pass 2: place (token, ex) — ex read is coalesced (sequential e)
#pragma unroll
    for (int i = 0; i < K3_EPT; ++i) {
        int off = i * K3_TPB + t;
        if (off >= nE) continue;
        int e = base + off;
        float exv = ex[e];
        int idx = idxv[i];
        int b = idx >> BSH;
        int pos = atomicAdd(&lcnt[b], 1);
        pairs[lbase[b] + pos] =
            make_uint2((unsigned)e | ((unsigned)(idx & (BNODES - 1)) << 21),
                       __float_as_uint(exv));
    }
}

// ---- K4: block per bucket — counting-sort chunk by node, register gather ----
__launch_bounds__(256)
__global__ void aggregate_kernel(const float* __restrict__ x,
                                 const uint2* __restrict__ pairs,
                                 const int* __restrict__ boff,
                                 const float* __restrict__ Wf,   // [DD][DD]
                                 const float* __restrict__ bfv,  // [DD]
                                 float* __restrict__ out, int N) {
    __shared__ uint2 sp[CHUNK];            // node-sorted (token, ex) of chunk
    __shared__ int cnt[BNODES];
    __shared__ int offs[BNODES + 1];
    __shared__ int cur[BNODES];

    int bk = blockIdx.x;
    int nbase = bk << BSH;
    int t = threadIdx.x;
    int wid = t >> 6;
    int lane = t & 63;
    int half = lane >> 5;
    int k = lane & 31;

    int beg = boff[bk], end = boff[bk + 1];

    float yacc[8], dacc[8];
#pragma unroll
    for (int s = 0; s < 8; ++s) { yacc[s] = 0.0f; dacc[s] = 0.0f; }

    for (int cb = beg; cb < end; cb += CHUNK) {
        int csz = min(CHUNK, end - cb);

        // coalesced load of this chunk's pairs into registers
        uint2 vreg[CPT];
#pragma unroll
        for (int j = 0; j < CPT; ++j) {
            int i = j * 256 + t;
            vreg[j].x = 0xFFFFFFFFu;
            if (i < csz) vreg[j] = pairs[cb + i];
        }

        if (t < BNODES) cnt[t] = 0;
        __syncthreads();
#pragma unroll
        for (int j = 0; j < CPT; ++j)
            if (vreg[j].x != 0xFFFFFFFFu)
                atomicAdd(&cnt[(vreg[j].x >> 21) & (BNODES - 1)], 1);
        __syncthreads();
        if (t == 0) {
            int r = 0;
            for (int n = 0; n < BNODES; ++n) { offs[n] = r; cur[n] = r; r += cnt[n]; }
            offs[BNODES] = r;
        }
        __syncthreads();
#pragma unroll
        for (int j = 0; j < CPT; ++j) {
            if (vreg[j].x != 0xFFFFFFFFu) {
                int nl = (vreg[j].x >> 21) & (BNODES - 1);
                int slot = atomicAdd(&cur[nl], 1);
                sp[slot] = vreg[j];
            }
        }
        __syncthreads();

        // register gather: wave wid owns nodes wid*8 .. wid*8+7
        // 8 x-rows in flight per half-wave (16 per wave)
#pragma unroll
        for (int s = 0; s < 8; ++s) {
            int nl = wid * 8 + s;
            int lo = offs[nl], hi = offs[nl + 1];
            float ya = 0.0f, da = 0.0f;
            int p = lo + half;
            for (; p + 14 < hi; p += 16) {
                uint2 a0 = sp[p],      a1 = sp[p + 2];
                uint2 a2 = sp[p + 4],  a3 = sp[p + 6];
                uint2 a4 = sp[p + 8],  a5 = sp[p + 10];
                uint2 a6 = sp[p + 12], a7 = sp[p + 14];
                float w0 = __uint_as_float(a0.y), w1 = __uint_as_float(a1.y);
                float w2 = __uint_as_float(a2.y), w3 = __uint_as_float(a3.y);
                float w4 = __uint_as_float(a4.y), w5 = __uint_as_float(a5.y);
                float w6 = __uint_as_float(a6.y), w7 = __uint_as_float(a7.y);
                float x0 = x[(size_t)(a0.x & 0x1FFFFFu) * DD + k];
                float x1 = x[(size_t)(a1.x & 0x1FFFFFu) * DD + k];
                float x2 = x[(size_t)(a2.x & 0x1FFFFFu) * DD + k];
                float x3 = x[(size_t)(a3.x & 0x1FFFFFu) * DD + k];
                float x4 = x[(size_t)(a4.x & 0x1FFFFFu) * DD + k];
                float x5 = x[(size_t)(a5.x & 0x1FFFFFu) * DD + k];
                float x6 = x[(size_t)(a6.x & 0x1FFFFFu) * DD + k];
                float x7 = x[(size_t)(a7.x & 0x1FFFFFu) * DD + k];
                ya = fmaf(w0, x0, ya); ya = fmaf(w1, x1, ya);
                ya = fmaf(w2, x2, ya); ya = fmaf(w3, x3, ya);
                ya = fmaf(w4, x4, ya); ya = fmaf(w5, x5, ya);
                ya = fmaf(w6, x6, ya); ya = fmaf(w7, x7, ya);
                da += ((w0 + w1) + (w2 + w3)) + ((w4 + w5) + (w6 + w7));
            }
            for (; p + 6 < hi; p += 8) {
                uint2 a0 = sp[p],     a1 = sp[p + 2];
                uint2 a2 = sp[p + 4], a3 = sp[p + 6];
                float w0 = __uint_as_float(a0.y), w1 = __uint_as_float(a1.y);
                float w2 = __uint_as_float(a2.y), w3 = __uint_as_float(a3.y);
                float x0 = x[(size_t)(a0.x & 0x1FFFFFu) * DD + k];
                float x1 = x[(size_t)(a1.x & 0x1FFFFFu) * DD + k];
                float x2 = x[(size_t)(a2.x & 0x1FFFFFu) * DD + k];
                float x3 = x[(size_t)(a3.x & 0x1FFFFFu) * DD + k];
                ya = fmaf(w0, x0, ya); ya = fmaf(w1, x1, ya);
                ya = fmaf(w2, x2, ya); ya = fmaf(w3, x3, ya);
                da += (w0 + w1) + (w2 + w3);
            }
            for (; p < hi; p += 2) {
                uint2 a = sp[p];
                float w = __uint_as_float(a.y);
                ya = fmaf(w, x[(size_t)(a.x & 0x1FFFFFu) * DD + k], ya);
                da += w;
            }
            yacc[s] += ya;
            dacc[s] += da;
        }
        __syncthreads();  // sp reused next chunk
    }

    // epilogue: combine halves, normalize, apply W, write
#pragma unroll
    for (int s = 0; s < 8; ++s) {
        float ya = yacc[s] + __shfl_xor(yacc[s], 32);
        float da = dacc[s] + __shfl_xor(dacc[s], 32);
        int node = nbase + wid * 8 + s;
        if (node < N) {
            float inv = 1.0f / (da + EPSF);
            float yn = ya * inv;
            float sw = da * inv;
            float o = sw * bfv[k];
#pragma unroll
            for (int kk = 0; kk < DD; ++kk)
                o = fmaf(__shfl(yn, kk), Wf[kk * DD + k], o);
            if (half == 0) out[(size_t)node * DD + k] = o;
        }
    }
}

extern "C" void kernel_launch(void* const* d_in, const int* in_sizes, int n_in,
                              void* d_out, int out_size, void* d_ws, size_t ws_size,
                              hipStream_t stream) {
    const float* x       = (const float*)d_in[0];
    const float* ax      = (const float*)d_in[1];
    const int*   index   = (const int*)d_in[2];
    // d_in[3] = size scalar; N derived from out_size
    const float* W_emb   = (const float*)d_in[4];
    const float* b_emb   = (const float*)d_in[5];
    const float* W_score = (const float*)d_in[6];
    const float* b_score = (const float*)d_in[7];

    int E = in_sizes[0] / DD;
    int N = out_size / DD;
    int B = (N + BNODES - 1) >> BSH;   // 1563 for N=50000 (<= BMAX)

    // workspace: pairs[E] 12.8 MB + ex[E] 6.4 MB + ~20 KB counters (ws ~800 MB)
    uint2* pairs   = (uint2*)d_ws;                    // [E]
    float* ex      = (float*)(pairs + (size_t)E);     // [E]
    int*   bcnt    = (int*)(ex + (size_t)E);          // [B]
    int*   boff    = bcnt + B;                        // [B+1]
    int*   bcursor = boff + B + 1;                    // [B]

    hipMemsetAsync(bcnt, 0, sizeof(int) * (size_t)B, stream);

    int blocksE2 = ((E + 1) / 2 + 255) / 256;
    score_kernel<<<blocksE2, 256, 0, stream>>>(ax, W_score, b_score, ex, E);

    int blocksK = (E + K3_EPB - 1) / K3_EPB;
    hist_kernel<<<blocksK, K3_TPB, 0, stream>>>(index, bcnt, E, B);
    scan_kernel<<<1, SCAN_T, 0, stream>>>(bcnt, boff, bcursor, B);
    bin_kernel<<<blocksK, K3_TPB, 0, stream>>>(index, ex, bcursor, pairs, E, B);
    aggregate_kernel<<<B, 256, 0, stream>>>(x, pairs, boff, W_emb, b_emb,
                                            (float*)d_out, N);
}